// Round 5
// baseline (1155.786 us; speedup 1.0000x reference)
//
#include <hip/hip_runtime.h>
#include <math.h>

// Problem constants
#define T_LEN  256
#define BATCH  32
#define EMBD   256
#define HHD    256           // per-direction hidden
#define NTAGS  12
#define NEGV   (-10000.0f)

typedef unsigned int u32x4 __attribute__((ext_vector_type(4)));

// R5: lgkm-only workgroup barrier, NO sched_barrier pins (R4's regression is
// attributed to the 4x sched_barrier(0)/step order-pinning, m141 failure
// mode). "memory" clobber orders all LDS/global accesses at compiler level;
// hardware LDS consistency needs only lgkmcnt(0) before s_barrier.
#define BAR_LGKM() asm volatile("s_waitcnt lgkmcnt(0)\n\ts_barrier" ::: "memory")

// ---------------------------------------------------------------------------
// Kernel 1: zx = gather(embed)[m,:] @ [W_ih_f | W_ih_b]^T + bias
// M = 8192 rows (m = t*32 + b), N = 2048, K = 256. 128x128x16 tile.
// R5: reverted to float4-store epilogue + plain layout (R0). The R3
// gate-interleaved layout made the epilogue scalar (16.7M 4B stores) and
// cost ~50us here for no lstm-side gain (the 4 scalar zx loads there are
// prefetched a full step ahead -> latency-irrelevant).
// ---------------------------------------------------------------------------
__global__ __launch_bounds__(256) void gemm_zx(
    const int* __restrict__ sentence, const float* __restrict__ embed,
    const float* __restrict__ Wf,  const float* __restrict__ Wb,
    const float* __restrict__ bf,  const float* __restrict__ bb,
    float* __restrict__ zx)
{
    __shared__ float As[16][132];
    __shared__ float Bs[16][132];

    const int tid = threadIdx.x;
    const int tx = tid & 15, ty = tid >> 4;
    const int Mbase = (int)(blockIdx.x >> 4) * 128;
    const int Nbase = (int)(blockIdx.x & 15) * 128;

    const float* Wsrc = (Nbase < 1024) ? Wf : Wb;
    const float* bsrc = (Nbase < 1024) ? bf : bb;
    const int nOff = (Nbase < 1024) ? Nbase : (Nbase - 1024);

    const int m0 = tid >> 2;
    const int m1 = m0 + 64;
    const int kq = (tid & 3) * 4;
    const int mg0 = Mbase + m0, mg1 = Mbase + m1;
    const int tok0 = sentence[(mg0 & 31) * T_LEN + (mg0 >> 5)];
    const int tok1 = sentence[(mg1 & 31) * T_LEN + (mg1 >> 5)];
    const float* arow0 = embed + (long long)tok0 * EMBD;
    const float* arow1 = embed + (long long)tok1 * EMBD;
    const float* brow0 = Wsrc + (long long)(nOff + m0) * EMBD;
    const float* brow1 = Wsrc + (long long)(nOff + m1) * EMBD;

    float acc[8][8];
#pragma unroll
    for (int i = 0; i < 8; ++i)
#pragma unroll
        for (int j = 0; j < 8; ++j) acc[i][j] = 0.0f;

    for (int k0 = 0; k0 < EMBD; k0 += 16) {
        float4 av0 = *(const float4*)(arow0 + k0 + kq);
        float4 av1 = *(const float4*)(arow1 + k0 + kq);
        float4 bv0 = *(const float4*)(brow0 + k0 + kq);
        float4 bv1 = *(const float4*)(brow1 + k0 + kq);
        __syncthreads();
        As[kq+0][m0] = av0.x; As[kq+1][m0] = av0.y; As[kq+2][m0] = av0.z; As[kq+3][m0] = av0.w;
        As[kq+0][m1] = av1.x; As[kq+1][m1] = av1.y; As[kq+2][m1] = av1.z; As[kq+3][m1] = av1.w;
        Bs[kq+0][m0] = bv0.x; Bs[kq+1][m0] = bv0.y; Bs[kq+2][m0] = bv0.z; Bs[kq+3][m0] = bv0.w;
        Bs[kq+0][m1] = bv1.x; Bs[kq+1][m1] = bv1.y; Bs[kq+2][m1] = bv1.z; Bs[kq+3][m1] = bv1.w;
        __syncthreads();
#pragma unroll
        for (int kt = 0; kt < 16; ++kt) {
            float am[8], bn[8];
            *(float4*)&am[0] = *(const float4*)&As[kt][ty * 4];
            *(float4*)&am[4] = *(const float4*)&As[kt][64 + ty * 4];
            *(float4*)&bn[0] = *(const float4*)&Bs[kt][tx * 4];
            *(float4*)&bn[4] = *(const float4*)&Bs[kt][64 + tx * 4];
#pragma unroll
            for (int i = 0; i < 8; ++i)
#pragma unroll
                for (int j = 0; j < 8; ++j) acc[i][j] += am[i] * bn[j];
        }
    }

    float4 bias0 = *(const float4*)(bsrc + nOff + tx * 4);
    float4 bias1 = *(const float4*)(bsrc + nOff + 64 + tx * 4);
    const float bnv[8] = {bias0.x, bias0.y, bias0.z, bias0.w,
                          bias1.x, bias1.y, bias1.z, bias1.w};
#pragma unroll
    for (int i = 0; i < 8; ++i) {
        const int mg = Mbase + ty * 4 + (i & 3) + ((i >= 4) ? 64 : 0);
        float4 o0 = make_float4(acc[i][0] + bnv[0], acc[i][1] + bnv[1],
                                acc[i][2] + bnv[2], acc[i][3] + bnv[3]);
        float4 o1 = make_float4(acc[i][4] + bnv[4], acc[i][5] + bnv[5],
                                acc[i][6] + bnv[6], acc[i][7] + bnv[7]);
        *(float4*)(zx + (long long)mg * 2048 + Nbase + tx * 4) = o0;
        *(float4*)(zx + (long long)mg * 2048 + Nbase + 64 + tx * 4) = o1;
    }
}

// ---------------------------------------------------------------------------
// Kernel 1b: pack W_hh into per-(slice,thread) contiguous 512 B chunks:
// offset = (((d*4+q)*2 + half)*256 + j)*128 + k2
//   j = gate-row within WG (g = j>>6, e = q*64 + (j&63)), k = half*128+k2.
// lstm_team WG with slice sl = d*4+q, thread tid reads chunk at tid*128.
// ---------------------------------------------------------------------------
__global__ __launch_bounds__(256) void pack_whh(
    const float* __restrict__ Whf, const float* __restrict__ Whb,
    float* __restrict__ pack)
{
    const int gid = blockIdx.x * 256 + threadIdx.x;   // 0..524287
    const int k2   = gid & 127;
    const int j    = (gid >> 7) & 255;
    const int half = (gid >> 15) & 1;
    const int q    = (gid >> 16) & 3;
    const int d    = (gid >> 18) & 1;
    const float* W = d ? Whb : Whf;
    const int g = j >> 6;
    const int e = q * 64 + (j & 63);
    pack[gid] = W[(g * 256 + e) * 256 + half * 128 + k2];
}

// ---------------------------------------------------------------------------
// Kernel 2: REGISTER-RESIDENT team LSTM.  256 WGs x 512 threads.
// R5: FLAG-ACCELERATED low-congestion exchange. R0(MALL)==R3(L2) at ~560us
// proved detect latency is CONGESTION-bound (poll storm), not transport-
// bound. New protocol:
//   producer (wave 0): 64 tagged u64 -> hxF (plain, XCD L2); vmcnt(0);
//     lane0 stores per-(par,d,b,q) FLAG = s+1; then lstm_out; then the
//     proven agent-scope tagged stores -> hxS (slow channel, ALWAYS written).
//   consumer (wave 1, 48 lanes = 3 groups x 16): group leader polls the
//     partner's FLAG only (3 poll streams/WG instead of 96; bounded 256
//     iters, no sleep); on flag: 2x dwordx4 sc0 bulk-read of the tagged
//     slots, tags re-verified (guards the non-colocated eviction race);
//     any failure -> latch fastOK=0 -> unbounded agent poll on hxS.
//   Hang-proof: every path terminates via hxS. Placement wrong => perf
//   only (one ~30us latch window), never correctness (G16).
// In-loop barriers: lgkm-only WITHOUT sched_barrier pins (R4 confound
// removed). Ping-pong overwrite safety: WG_A overwrites its parity slot at
// step s+2 only after observing partners' tag-(s+2) data, which requires
// partners' consumers to have read A's tag-(s+1) slot (observation implies
// L2 commit) -> no same-address store overlap.
// blockIdx remap: partners differ only in bits 4:3 -> same bx%8 AND same
// bx/32 -> co-located under round-robin OR chunked dispatch (perf only).
// W pinned via empty inline-asm "+v" (blocks rematerialization).
// ---------------------------------------------------------------------------
__global__ __launch_bounds__(512, 2) void lstm_team(
    const float* __restrict__ zx, const float* __restrict__ pack,
    const float* __restrict__ h0, const float* __restrict__ c0,
    unsigned long long* __restrict__ hxF,   // fast: [2 par][2 d][32 b][256 e]
    unsigned long long* __restrict__ hxS,   // slow: same layout
    unsigned int* __restrict__ flagF,       // [2 par][2 d][32 b][4 q] x16 pad
    float* __restrict__ lstm_out)
{
    __shared__ float hS0[256];
    __shared__ float hS1[256];
    __shared__ float pS[512];

    const int tid = threadIdx.x;
    const int bx  = (int)blockIdx.x;
    const int b  = ((bx >> 5) & 3) * 8 + (bx & 7);
    const int q  = (bx >> 3) & 3;
    const int d  = (bx >> 7) & 1;
    const int sl = d * 4 + q;

    // --- W half-row into registers (one-time, coalesced) ---
    float4 wreg[32];
    {
        const float4* wrow = (const float4*)(pack + ((long long)sl << 16)
                                             + tid * 128);
#pragma unroll
        for (int c = 0; c < 32; ++c) wreg[c] = wrow[c];
    }
    // Forbid rematerialization: values become asm outputs, not loads.
#pragma unroll
    for (int c = 0; c < 32; ++c) {
        asm volatile("" : "+v"(wreg[c].x), "+v"(wreg[c].y),
                          "+v"(wreg[c].z), "+v"(wreg[c].w));
    }

    const int half = tid >> 8;            // k-half this thread dots
    const long long hxbase = (long long)(d * 32 + b) * 256;
    float creg = (tid < 64) ? c0[(d * 32 + b) * 256 + q * 64 + tid] : 0.0f;
    int fastOK = 1;

    // consumer roles: wave 1 lanes 0..47 = 3 groups x 16, one partner each
    const int li = tid - 64;              // wave-1 lane id (0..63)
    const int pg = li >> 4;               // group 0..3
    const int pk = li & 15;               // lane within group
    int e0p = -1, qq = 0;
    if (li >= 0 && li < 48) {
        qq = pg + (pg >= q);              // partner quarter (skip own)
        e0p = qq * 64 + pk * 4;           // this lane fills 4 h-elements
    }

    if (tid < 256) hS0[tid] = h0[(d * 32 + b) * 256 + tid];
    __syncthreads();

    // zx pipeline: current step's 4 gate pre-activations, one step ahead
    const int zco = d * 1024 + q * 64 + (tid & 63);
    float zv0 = 0.f, zv1 = 0.f, zv2 = 0.f, zv3 = 0.f;
    if (tid < 64) {
        const int t0 = d ? (T_LEN - 1) : 0;
        const float* zr = zx + (long long)(t0 * 32 + b) * 2048 + zco;
        zv0 = zr[0]; zv1 = zr[256]; zv2 = zr[512]; zv3 = zr[768];
    }

    for (int s = 0; s < T_LEN; ++s) {
        const int t = d ? (T_LEN - 1 - s) : s;

        // prefetch NEXT step's zx (full step of latency slack)
        float zn0 = zv0, zn1 = zv1, zn2 = zv2, zn3 = zv3;
        if (tid < 64 && s < T_LEN - 1) {
            const int tn = d ? (T_LEN - 2 - s) : (s + 1);
            const float* zr = zx + (long long)(tn * 32 + b) * 2048 + zco;
            zn0 = zr[0]; zn1 = zr[256]; zn2 = zr[512]; zn3 = zr[768];
        }

        const float* h  = (s & 1) ? hS1 : hS0;
        float*       hN = (s & 1) ? hS0 : hS1;
        const float* hh = h + half * 128;   // wave-uniform -> LDS broadcast

        // --- half-dot from registers ---
        float a = 0.0f;
#pragma unroll
        for (int c = 0; c < 32; ++c) {
            const float4 hv = *(const float4*)(hh + c * 4);
            a += wreg[c].x * hv.x + wreg[c].y * hv.y
               + wreg[c].z * hv.z + wreg[c].w * hv.w;
        }
        pS[tid] = a;
        BAR_LGKM();

        const int parN = (s & 1) ^ 1;
        if (tid < 64) {
            const float zi = pS[tid]       + pS[tid + 256] + zv0;
            const float zf = pS[tid + 64]  + pS[tid + 320] + zv1;
            const float zg = pS[tid + 128] + pS[tid + 384] + zv2;
            const float zo = pS[tid + 192] + pS[tid + 448] + zv3;
            const float si = 1.0f / (1.0f + expf(-zi));
            const float sf = 1.0f / (1.0f + expf(-zf));
            const float so = 1.0f / (1.0f + expf(-zo));
            creg = sf * creg + si * tanhf(zg);
            const float hn = so * tanhf(creg);
            const int e = q * 64 + tid;
            hN[e] = hn;
            const unsigned long long tv =
                ((unsigned long long)(unsigned)(s + 1) << 32)
                    | (unsigned long long)__float_as_uint(hn);
            const long long off = (long long)parN * 16384 + hxbase + e;
            // 1) fast data (tagged) -> producer-XCD L2
            *(volatile unsigned long long*)(hxF + off) = tv;
            // 2) ensure data committed before the flag
            asm volatile("s_waitcnt vmcnt(0)" ::: "memory");
            // 3) flag: one store per WG
            if (tid == 0) {
                volatile unsigned int* fp =
                    flagF + ((((long long)parN * 2 + d) * 32 + b) * 4 + q) * 16;
                *fp = (unsigned)(s + 1);
            }
            // 4) off-critical-path stores
            lstm_out[(long long)(t * 32 + b) * 512 + d * 256 + e] = hn;
            __hip_atomic_store(hxS + off, tv, __ATOMIC_RELAXED,
                               __HIP_MEMORY_SCOPE_AGENT);     // proven slow
        } else if (e0p >= 0 && s < T_LEN - 1) {
            const long long off = (long long)parN * 16384 + hxbase + e0p;
            const unsigned tag = (unsigned)(s + 1);
            int got = 0;
            if (pk == 0 && fastOK) {
                const unsigned int* fp =
                    flagF + ((((long long)parN * 2 + d) * 32 + b) * 4 + qq) * 16;
                for (int it = 0; it < 256; ++it) {
                    unsigned fv;
                    asm volatile(
                        "global_load_dword %0, %1, off sc0\n\t"
                        "s_waitcnt vmcnt(0)"
                        : "=&v"(fv) : "v"(fp) : "memory");
                    if (fv == tag) { got = 1; break; }
                }
                if (!got) fastOK = 0;   // latch: never retry fast
            }
            got = __shfl(got, pg << 4); // broadcast group leader's verdict
            if (got) {
                u32x4 v0, v1;
                const unsigned long long* fp0 = hxF + off;
                asm volatile(
                    "global_load_dwordx4 %0, %2, off sc0\n\t"
                    "global_load_dwordx4 %1, %3, off sc0\n\t"
                    "s_waitcnt vmcnt(0)"
                    : "=&v"(v0), "=&v"(v1) : "v"(fp0), "v"(fp0 + 2)
                    : "memory");
                if (v0.y == tag && v0.z + 0u == v0.z && v0.w == tag &&
                    v1.y == tag && v1.w == tag) {
                    *(float4*)&hN[e0p] = make_float4(
                        __uint_as_float(v0.x), __uint_as_float(v0.z),
                        __uint_as_float(v1.x), __uint_as_float(v1.z));
                } else {
                    got = 0;            // eviction race (non-colocated)
                }
            }
            if (!got) {
                // slow: per-slot unbounded agent poll (always terminates)
#pragma unroll
                for (int j = 0; j < 4; ++j) {
                    unsigned long long v;
                    const unsigned long long* sp = hxS + off + j;
                    do { v = __hip_atomic_load(sp, __ATOMIC_RELAXED,
                                               __HIP_MEMORY_SCOPE_AGENT);
                    } while ((unsigned)(v >> 32) != tag);
                    hN[e0p + j] = __uint_as_float((unsigned)v);
                }
            }
        }
        zv0 = zn0; zv1 = zn1; zv2 = zn2; zv3 = zn3;
        BAR_LGKM();
    }
}

// ---------------------------------------------------------------------------
// Kernel 3: feats = lstm_out @ W_out^T + b_out
// ---------------------------------------------------------------------------
__global__ __launch_bounds__(256) void feats_kernel(
    const float* __restrict__ lstm_out, const float* __restrict__ W_out,
    const float* __restrict__ b_out, float* __restrict__ feats)
{
    const int gid = blockIdx.x * 256 + threadIdx.x;
    if (gid >= 8192 * NTAGS) return;
    const int row = gid / NTAGS;
    const int tag = gid - row * NTAGS;
    const float4* x = (const float4*)(lstm_out + (long long)row * 512);
    const float4* w = (const float4*)(W_out + (long long)tag * 512);
    float acc = b_out[tag];
#pragma unroll 4
    for (int k = 0; k < 128; ++k) {
        float4 a = x[k], bw = w[k];
        acc += a.x * bw.x + a.y * bw.y + a.z * bw.z + a.w * bw.w;
    }
    const int t = row >> 5, b = row & 31;
    feats[(long long)b * (T_LEN * NTAGS) + t * NTAGS + tag] = acc;
}

// ---------------------------------------------------------------------------
// Kernel 4: Viterbi per batch. 32 WGs x 64 threads.
// ---------------------------------------------------------------------------
__global__ __launch_bounds__(64) void viterbi_kernel(
    const float* __restrict__ feats, const float* __restrict__ trans,
    float* __restrict__ out)
{
    __shared__ float featS[T_LEN * NTAGS];
    __shared__ float transS[NTAGS * NTAGS];
    __shared__ float fvS[NTAGS];
    __shared__ unsigned char bpS[T_LEN][NTAGS];
    __shared__ float pathS[T_LEN];

    const int b = blockIdx.x;
    const int lane = threadIdx.x;

    {
        const float4* src = (const float4*)(feats + (long long)b * (T_LEN * NTAGS));
        float4* dst = (float4*)featS;
        for (int i = lane; i < (T_LEN * NTAGS) / 4; i += 64) dst[i] = src[i];
        for (int i = lane; i < NTAGS * NTAGS; i += 64) transS[i] = trans[i];
    }
    __syncthreads();

    float fv[NTAGS];
#pragma unroll
    for (int p = 0; p < NTAGS; ++p) fv[p] = (p == 10) ? 0.0f : NEGV;

    for (int t = 0; t < T_LEN; ++t) {
        if (lane < NTAGS) {
            float best = -3.4e38f; int bi = 0;
#pragma unroll
            for (int p = 0; p < NTAGS; ++p) {
                const float v = fv[p] + transS[lane * NTAGS + p];
                if (v > best) { best = v; bi = p; }
            }
            bpS[t][lane] = (unsigned char)bi;
            fvS[lane] = best + featS[t * NTAGS + lane];
        }
        __syncthreads();
#pragma unroll
        for (int p = 0; p < NTAGS; ++p) fv[p] = fvS[p];
        __syncthreads();
    }

    if (lane < NTAGS) fvS[lane] = fv[lane] + transS[11 * NTAGS + lane];
    __syncthreads();
    if (lane == 0) {
        float best = -3.4e38f; int bi = 0;
        for (int p = 0; p < NTAGS; ++p) {
            const float v = fvS[p];
            if (v > best) { best = v; bi = p; }
        }
        out[b] = best;
        int cur = bi;
        pathS[T_LEN - 1] = (float)cur;
        for (int tt = T_LEN - 2; tt >= 0; --tt) {
            cur = bpS[tt + 1][cur];
            pathS[tt] = (float)cur;
        }
    }
    __syncthreads();
    float* po = out + BATCH + (long long)b * T_LEN;
    for (int i = lane; i < T_LEN; i += 64) po[i] = pathS[i];
}

// ---------------------------------------------------------------------------
extern "C" void kernel_launch(void* const* d_in, const int* in_sizes, int n_in,
                              void* d_out, int out_size, void* d_ws, size_t ws_size,
                              hipStream_t stream)
{
    (void)in_sizes; (void)n_in; (void)out_size; (void)ws_size;
    const int*   sentence = (const int*)  d_in[0];
    const float* embed    = (const float*)d_in[1];
    const float* W_ih_f   = (const float*)d_in[2];
    const float* W_hh_f   = (const float*)d_in[3];
    const float* b_f      = (const float*)d_in[4];
    const float* W_ih_b   = (const float*)d_in[5];
    const float* W_hh_b   = (const float*)d_in[6];
    const float* b_b      = (const float*)d_in[7];
    const float* W_out    = (const float*)d_in[8];
    const float* b_out    = (const float*)d_in[9];
    const float* trans    = (const float*)d_in[10];
    const float* h0       = (const float*)d_in[11];
    const float* c0       = (const float*)d_in[12];
    float* out = (float*)d_out;

    char* ws = (char*)d_ws;
    float* zx       = (float*)ws; ws += (long long)8192 * 2048 * 4;   // 64 MB
    float* lstm_out = (float*)ws; ws += (long long)8192 * 512 * 4;    // 16 MB
    float* feats    = (float*)ws; ws += BATCH * T_LEN * NTAGS * 4;    // 384 KB
    float* pack     = (float*)ws; ws += (long long)524288 * 4;        // 2 MB
    unsigned long long* hxS = (unsigned long long*)ws; ws += 2 * 16384 * 8; // 256 KB
    unsigned long long* hxF = (unsigned long long*)ws; ws += 2 * 16384 * 8; // 256 KB
    unsigned int* flagF = (unsigned int*)ws; ws += 2 * 2 * 32 * 4 * 16 * 4; // 32 KB
    // hxS/hxF/flagF re-poisoned to 0xAA before every launch -> tags invalid.

    pack_whh<<<2048, 256, 0, stream>>>(W_hh_f, W_hh_b, pack);
    gemm_zx<<<1024, 256, 0, stream>>>(sentence, embed, W_ih_f, W_ih_b, b_f, b_b, zx);
    lstm_team<<<256, 512, 0, stream>>>(zx, pack, h0, c0, hxF, hxS, flagF, lstm_out);
    feats_kernel<<<384, 256, 0, stream>>>(lstm_out, W_out, b_out, feats);
    viterbi_kernel<<<32, 64, 0, stream>>>(feats, trans, out);
}

// Round 6
// 785.008 us; speedup vs baseline: 1.4723x; 1.4723x over previous
//
#include <hip/hip_runtime.h>
#include <math.h>

// Problem constants
#define T_LEN  256
#define BATCH  32
#define EMBD   256
#define HHD    256           // per-direction hidden
#define NTAGS  12
#define NEGV   (-10000.0f)

// Zero-instruction register pins: force all 16 floats to live in VGPRs at
// this program point. Used per-iteration so the allocator can never spill
// the W tile (reloading 128 regs before every pin is strictly worse than
// keeping them resident).
#define PIN4(r0,r1,r2,r3)                                                  \
    asm volatile("" : "+v"(r0.x),"+v"(r0.y),"+v"(r0.z),"+v"(r0.w),         \
                      "+v"(r1.x),"+v"(r1.y),"+v"(r1.z),"+v"(r1.w),         \
                      "+v"(r2.x),"+v"(r2.y),"+v"(r2.z),"+v"(r2.w),         \
                      "+v"(r3.x),"+v"(r3.y),"+v"(r3.z),"+v"(r3.w))

#define PIN_ALL_W() do {                                                   \
    PIN4(wreg[0],wreg[1],wreg[2],wreg[3]);                                 \
    PIN4(wreg[4],wreg[5],wreg[6],wreg[7]);                                 \
    PIN4(wreg[8],wreg[9],wreg[10],wreg[11]);                               \
    PIN4(wreg[12],wreg[13],wreg[14],wreg[15]);                             \
    PIN4(wreg[16],wreg[17],wreg[18],wreg[19]);                             \
    PIN4(wreg[20],wreg[21],wreg[22],wreg[23]);                             \
    PIN4(wreg[24],wreg[25],wreg[26],wreg[27]);                             \
    PIN4(wreg[28],wreg[29],wreg[30],wreg[31]);                             \
} while (0)

// ---------------------------------------------------------------------------
// Kernel 1: zx = gather(embed)[m,:] @ [W_ih_f | W_ih_b]^T + bias
// M = 8192 rows (m = t*32 + b), N = 2048, K = 256. 128x128x16 tile.
// Plain layout + float4 epilogue (R5 revert, kept).
// ---------------------------------------------------------------------------
__global__ __launch_bounds__(256) void gemm_zx(
    const int* __restrict__ sentence, const float* __restrict__ embed,
    const float* __restrict__ Wf,  const float* __restrict__ Wb,
    const float* __restrict__ bf,  const float* __restrict__ bb,
    float* __restrict__ zx)
{
    __shared__ float As[16][132];
    __shared__ float Bs[16][132];

    const int tid = threadIdx.x;
    const int tx = tid & 15, ty = tid >> 4;
    const int Mbase = (int)(blockIdx.x >> 4) * 128;
    const int Nbase = (int)(blockIdx.x & 15) * 128;

    const float* Wsrc = (Nbase < 1024) ? Wf : Wb;
    const float* bsrc = (Nbase < 1024) ? bf : bb;
    const int nOff = (Nbase < 1024) ? Nbase : (Nbase - 1024);

    const int m0 = tid >> 2;
    const int m1 = m0 + 64;
    const int kq = (tid & 3) * 4;
    const int mg0 = Mbase + m0, mg1 = Mbase + m1;
    const int tok0 = sentence[(mg0 & 31) * T_LEN + (mg0 >> 5)];
    const int tok1 = sentence[(mg1 & 31) * T_LEN + (mg1 >> 5)];
    const float* arow0 = embed + (long long)tok0 * EMBD;
    const float* arow1 = embed + (long long)tok1 * EMBD;
    const float* brow0 = Wsrc + (long long)(nOff + m0) * EMBD;
    const float* brow1 = Wsrc + (long long)(nOff + m1) * EMBD;

    float acc[8][8];
#pragma unroll
    for (int i = 0; i < 8; ++i)
#pragma unroll
        for (int j = 0; j < 8; ++j) acc[i][j] = 0.0f;

    for (int k0 = 0; k0 < EMBD; k0 += 16) {
        float4 av0 = *(const float4*)(arow0 + k0 + kq);
        float4 av1 = *(const float4*)(arow1 + k0 + kq);
        float4 bv0 = *(const float4*)(brow0 + k0 + kq);
        float4 bv1 = *(const float4*)(brow1 + k0 + kq);
        __syncthreads();
        As[kq+0][m0] = av0.x; As[kq+1][m0] = av0.y; As[kq+2][m0] = av0.z; As[kq+3][m0] = av0.w;
        As[kq+0][m1] = av1.x; As[kq+1][m1] = av1.y; As[kq+2][m1] = av1.z; As[kq+3][m1] = av1.w;
        Bs[kq+0][m0] = bv0.x; Bs[kq+1][m0] = bv0.y; Bs[kq+2][m0] = bv0.z; Bs[kq+3][m0] = bv0.w;
        Bs[kq+0][m1] = bv1.x; Bs[kq+1][m1] = bv1.y; Bs[kq+2][m1] = bv1.z; Bs[kq+3][m1] = bv1.w;
        __syncthreads();
#pragma unroll
        for (int kt = 0; kt < 16; ++kt) {
            float am[8], bn[8];
            *(float4*)&am[0] = *(const float4*)&As[kt][ty * 4];
            *(float4*)&am[4] = *(const float4*)&As[kt][64 + ty * 4];
            *(float4*)&bn[0] = *(const float4*)&Bs[kt][tx * 4];
            *(float4*)&bn[4] = *(const float4*)&Bs[kt][64 + tx * 4];
#pragma unroll
            for (int i = 0; i < 8; ++i)
#pragma unroll
                for (int j = 0; j < 8; ++j) acc[i][j] += am[i] * bn[j];
        }
    }

    float4 bias0 = *(const float4*)(bsrc + nOff + tx * 4);
    float4 bias1 = *(const float4*)(bsrc + nOff + 64 + tx * 4);
    const float bnv[8] = {bias0.x, bias0.y, bias0.z, bias0.w,
                          bias1.x, bias1.y, bias1.z, bias1.w};
#pragma unroll
    for (int i = 0; i < 8; ++i) {
        const int mg = Mbase + ty * 4 + (i & 3) + ((i >= 4) ? 64 : 0);
        float4 o0 = make_float4(acc[i][0] + bnv[0], acc[i][1] + bnv[1],
                                acc[i][2] + bnv[2], acc[i][3] + bnv[3]);
        float4 o1 = make_float4(acc[i][4] + bnv[4], acc[i][5] + bnv[5],
                                acc[i][6] + bnv[6], acc[i][7] + bnv[7]);
        *(float4*)(zx + (long long)mg * 2048 + Nbase + tx * 4) = o0;
        *(float4*)(zx + (long long)mg * 2048 + Nbase + 64 + tx * 4) = o1;
    }
}

// ---------------------------------------------------------------------------
// Kernel 1b: pack W_hh into per-(slice,thread) contiguous 512 B chunks:
// offset = (((d*4+q)*2 + half)*256 + j)*128 + k2
//   j = gate-row within WG (g = j>>6, e = q*64 + (j&63)), k = half*128+k2.
// lstm_team WG with slice sl = d*4+q, thread tid reads chunk at tid*128.
// ---------------------------------------------------------------------------
__global__ __launch_bounds__(256) void pack_whh(
    const float* __restrict__ Whf, const float* __restrict__ Whb,
    float* __restrict__ pack)
{
    const int gid = blockIdx.x * 256 + threadIdx.x;   // 0..524287
    const int k2   = gid & 127;
    const int j    = (gid >> 7) & 255;
    const int half = (gid >> 15) & 1;
    const int q    = (gid >> 16) & 3;
    const int d    = (gid >> 18) & 1;
    const float* W = d ? Whb : Whf;
    const int g = j >> 6;
    const int e = q * 64 + (j & 63);
    pack[gid] = W[(g * 256 + e) * 256 + half * 128 + k2];
}

// ---------------------------------------------------------------------------
// Kernel 2: REGISTER-RESIDENT team LSTM.  256 WGs x 512 threads.
// R6 DIAGNOSIS: VGPR_Count=100-104 in EVERY round => wreg (needs 128 VGPR)
// was NEVER resident; the one-time asm pin is defeated (spill/re-stream).
// Per-CU W traffic 512thr x 512B = 256KB/step through L1<-L2 at ~115GB/s/CU
// = 2.2us/step = EXACTLY the invariant 555-565us floor. All five exchange
// protocols were masked by this; R0==R3 is explained.
// FIX:
//   (1) __launch_bounds__(512, 1): VGPR cap 256 -> 512; ~170 needed fits
//       with huge headroom. Occupancy unaffected: 256 WGs on 256 CUs is
//       1 WG/CU regardless (prior session ran ~175 VGPR in this shape).
//   (2) PIN_ALL_W() at the top of EVERY s-iteration: zero-instruction asm
//       that forces all 128 W components into VGPRs at each iteration =>
//       spilling would cost a full reload per step; allocator keeps W
//       resident.
// Exchange: reverted to the R0-proven single agent-scope channel (equal-
// best, simplest, lowest register pressure; dual-channel/flag machinery
// removed). zx prefetched one full step ahead. Plain __syncthreads()
// barriers (isolate ONE variable this round: W residency).
// VERIFY next counters: VGPR_Count >= ~160, else the fix failed.
// ---------------------------------------------------------------------------
__global__ __launch_bounds__(512, 1) void lstm_team(
    const float* __restrict__ zx, const float* __restrict__ pack,
    const float* __restrict__ h0, const float* __restrict__ c0,
    unsigned long long* __restrict__ hx,   // [2 par][2 d][32 b][256 e]
    float* __restrict__ lstm_out)
{
    __shared__ float hS0[256];
    __shared__ float hS1[256];
    __shared__ float pS[512];

    const int tid = threadIdx.x;
    const int bx  = (int)blockIdx.x;
    const int b  = ((bx >> 5) & 3) * 8 + (bx & 7);
    const int q  = (bx >> 3) & 3;
    const int d  = (bx >> 7) & 1;
    const int sl = d * 4 + q;

    // --- W half-row into registers (one-time, coalesced) ---
    float4 wreg[32];
    {
        const float4* wrow = (const float4*)(pack + ((long long)sl << 16)
                                             + tid * 128);
#pragma unroll
        for (int c = 0; c < 32; ++c) wreg[c] = wrow[c];
    }
    PIN_ALL_W();

    const int half = tid >> 8;            // k-half this thread dots
    const long long hxbase = (long long)(d * 32 + b) * 256;
    float creg = (tid < 64) ? c0[(d * 32 + b) * 256 + q * 64 + tid] : 0.0f;

    if (tid < 256) hS0[tid] = h0[(d * 32 + b) * 256 + tid];
    __syncthreads();

    // zx pipeline: current step's 4 gate pre-activations, one step ahead
    const int zco = d * 1024 + q * 64 + (tid & 63);
    float zv0 = 0.f, zv1 = 0.f, zv2 = 0.f, zv3 = 0.f;
    if (tid < 64) {
        const int t0 = d ? (T_LEN - 1) : 0;
        const float* zr = zx + (long long)(t0 * 32 + b) * 2048 + zco;
        zv0 = zr[0]; zv1 = zr[256]; zv2 = zr[512]; zv3 = zr[768];
    }

    for (int s = 0; s < T_LEN; ++s) {
        PIN_ALL_W();                       // per-step residency enforcement
        const int t = d ? (T_LEN - 1 - s) : s;

        // prefetch NEXT step's zx (full step of latency slack)
        float zn0 = zv0, zn1 = zv1, zn2 = zv2, zn3 = zv3;
        if (tid < 64 && s < T_LEN - 1) {
            const int tn = d ? (T_LEN - 2 - s) : (s + 1);
            const float* zr = zx + (long long)(tn * 32 + b) * 2048 + zco;
            zn0 = zr[0]; zn1 = zr[256]; zn2 = zr[512]; zn3 = zr[768];
        }

        const float* h  = (s & 1) ? hS1 : hS0;
        float*       hN = (s & 1) ? hS0 : hS1;
        const float* hh = h + half * 128;   // wave-uniform -> LDS broadcast

        // --- half-dot from registers ---
        float a = 0.0f;
#pragma unroll
        for (int c = 0; c < 32; ++c) {
            const float4 hv = *(const float4*)(hh + c * 4);
            a += wreg[c].x * hv.x + wreg[c].y * hv.y
               + wreg[c].z * hv.z + wreg[c].w * hv.w;
        }
        pS[tid] = a;
        __syncthreads();

        const int parN = (s & 1) ^ 1;
        if (tid < 64) {
            const float zi = pS[tid]       + pS[tid + 256] + zv0;
            const float zf = pS[tid + 64]  + pS[tid + 320] + zv1;
            const float zg = pS[tid + 128] + pS[tid + 384] + zv2;
            const float zo = pS[tid + 192] + pS[tid + 448] + zv3;
            const float si = 1.0f / (1.0f + expf(-zi));
            const float sf = 1.0f / (1.0f + expf(-zf));
            const float so = 1.0f / (1.0f + expf(-zo));
            creg = sf * creg + si * tanhf(zg);
            const float hn = so * tanhf(creg);
            const int e = q * 64 + tid;
            hN[e] = hn;
            lstm_out[(long long)(t * 32 + b) * 512 + d * 256 + e] = hn;
            __hip_atomic_store(hx + (long long)parN * 16384 + hxbase + e,
                ((unsigned long long)(unsigned)(s + 1) << 32)
                    | (unsigned long long)__float_as_uint(hn),
                __ATOMIC_RELAXED, __HIP_MEMORY_SCOPE_AGENT);
        } else if (s < T_LEN - 1) {
            int e = -1;
            if (tid < 256) { if ((tid >> 6) != q) e = tid; }
            else if (tid < 320) { if (q != 0) e = tid - 256; }
            if (e >= 0) {
                const unsigned long long* slot =
                    hx + (long long)parN * 16384 + hxbase + e;
                unsigned long long v;
                do {
                    v = __hip_atomic_load(slot, __ATOMIC_RELAXED,
                                          __HIP_MEMORY_SCOPE_AGENT);
                } while ((unsigned)(v >> 32) != (unsigned)(s + 1));
                hN[e] = __uint_as_float((unsigned)v);
            }
        }
        zv0 = zn0; zv1 = zn1; zv2 = zn2; zv3 = zn3;
        __syncthreads();
    }
}

// ---------------------------------------------------------------------------
// Kernel 3: feats = lstm_out @ W_out^T + b_out
// ---------------------------------------------------------------------------
__global__ __launch_bounds__(256) void feats_kernel(
    const float* __restrict__ lstm_out, const float* __restrict__ W_out,
    const float* __restrict__ b_out, float* __restrict__ feats)
{
    const int gid = blockIdx.x * 256 + threadIdx.x;
    if (gid >= 8192 * NTAGS) return;
    const int row = gid / NTAGS;
    const int tag = gid - row * NTAGS;
    const float4* x = (const float4*)(lstm_out + (long long)row * 512);
    const float4* w = (const float4*)(W_out + (long long)tag * 512);
    float acc = b_out[tag];
#pragma unroll 4
    for (int k = 0; k < 128; ++k) {
        float4 a = x[k], bw = w[k];
        acc += a.x * bw.x + a.y * bw.y + a.z * bw.z + a.w * bw.w;
    }
    const int t = row >> 5, b = row & 31;
    feats[(long long)b * (T_LEN * NTAGS) + t * NTAGS + tag] = acc;
}

// ---------------------------------------------------------------------------
// Kernel 4: Viterbi per batch. 32 WGs x 64 threads.
// ---------------------------------------------------------------------------
__global__ __launch_bounds__(64) void viterbi_kernel(
    const float* __restrict__ feats, const float* __restrict__ trans,
    float* __restrict__ out)
{
    __shared__ float featS[T_LEN * NTAGS];
    __shared__ float transS[NTAGS * NTAGS];
    __shared__ float fvS[NTAGS];
    __shared__ unsigned char bpS[T_LEN][NTAGS];
    __shared__ float pathS[T_LEN];

    const int b = blockIdx.x;
    const int lane = threadIdx.x;

    {
        const float4* src = (const float4*)(feats + (long long)b * (T_LEN * NTAGS));
        float4* dst = (float4*)featS;
        for (int i = lane; i < (T_LEN * NTAGS) / 4; i += 64) dst[i] = src[i];
        for (int i = lane; i < NTAGS * NTAGS; i += 64) transS[i] = trans[i];
    }
    __syncthreads();

    float fv[NTAGS];
#pragma unroll
    for (int p = 0; p < NTAGS; ++p) fv[p] = (p == 10) ? 0.0f : NEGV;

    for (int t = 0; t < T_LEN; ++t) {
        if (lane < NTAGS) {
            float best = -3.4e38f; int bi = 0;
#pragma unroll
            for (int p = 0; p < NTAGS; ++p) {
                const float v = fv[p] + transS[lane * NTAGS + p];
                if (v > best) { best = v; bi = p; }
            }
            bpS[t][lane] = (unsigned char)bi;
            fvS[lane] = best + featS[t * NTAGS + lane];
        }
        __syncthreads();
#pragma unroll
        for (int p = 0; p < NTAGS; ++p) fv[p] = fvS[p];
        __syncthreads();
    }

    if (lane < NTAGS) fvS[lane] = fv[lane] + transS[11 * NTAGS + lane];
    __syncthreads();
    if (lane == 0) {
        float best = -3.4e38f; int bi = 0;
        for (int p = 0; p < NTAGS; ++p) {
            const float v = fvS[p];
            if (v > best) { best = v; bi = p; }
        }
        out[b] = best;
        int cur = bi;
        pathS[T_LEN - 1] = (float)cur;
        for (int tt = T_LEN - 2; tt >= 0; --tt) {
            cur = bpS[tt + 1][cur];
            pathS[tt] = (float)cur;
        }
    }
    __syncthreads();
    float* po = out + BATCH + (long long)b * T_LEN;
    for (int i = lane; i < T_LEN; i += 64) po[i] = pathS[i];
}

// ---------------------------------------------------------------------------
extern "C" void kernel_launch(void* const* d_in, const int* in_sizes, int n_in,
                              void* d_out, int out_size, void* d_ws, size_t ws_size,
                              hipStream_t stream)
{
    (void)in_sizes; (void)n_in; (void)out_size; (void)ws_size;
    const int*   sentence = (const int*)  d_in[0];
    const float* embed    = (const float*)d_in[1];
    const float* W_ih_f   = (const float*)d_in[2];
    const float* W_hh_f   = (const float*)d_in[3];
    const float* b_f      = (const float*)d_in[4];
    const float* W_ih_b   = (const float*)d_in[5];
    const float* W_hh_b   = (const float*)d_in[6];
    const float* b_b      = (const float*)d_in[7];
    const float* W_out    = (const float*)d_in[8];
    const float* b_out    = (const float*)d_in[9];
    const float* trans    = (const float*)d_in[10];
    const float* h0       = (const float*)d_in[11];
    const float* c0       = (const float*)d_in[12];
    float* out = (float*)d_out;

    char* ws = (char*)d_ws;
    float* zx       = (float*)ws; ws += (long long)8192 * 2048 * 4;   // 64 MB
    float* lstm_out = (float*)ws; ws += (long long)8192 * 512 * 4;    // 16 MB
    float* feats    = (float*)ws; ws += BATCH * T_LEN * NTAGS * 4;    // 384 KB
    float* pack     = (float*)ws; ws += (long long)524288 * 4;        // 2 MB
    unsigned long long* hx = (unsigned long long*)ws; ws += 2 * 16384 * 8; // 256 KB
    // hx re-poisoned to 0xAA before every launch -> tags invalid. No memset.

    pack_whh<<<2048, 256, 0, stream>>>(W_hh_f, W_hh_b, pack);
    gemm_zx<<<1024, 256, 0, stream>>>(sentence, embed, W_ih_f, W_ih_b, b_f, b_b, zx);
    lstm_team<<<256, 512, 0, stream>>>(zx, pack, h0, c0, hx, lstm_out);
    feats_kernel<<<384, 256, 0, stream>>>(lstm_out, W_out, b_out, feats);
    viterbi_kernel<<<32, 64, 0, stream>>>(feats, trans, out);
}